// Round 11
// baseline (578.734 us; speedup 1.0000x reference)
//
#include <hip/hip_runtime.h>
#include <hip/hip_bf16.h>

typedef __attribute__((ext_vector_type(8))) short bfrag_t;
typedef __attribute__((ext_vector_type(4))) short s4_t;
typedef __attribute__((ext_vector_type(4))) float facc_t;
typedef __attribute__((ext_vector_type(16))) float f16acc_t;
typedef __attribute__((ext_vector_type(4))) int i4_t;

#define B_ 4
#define S_ 4096
#define D_ 256

using gas_v = const __attribute__((address_space(1))) void;
using las_v = __attribute__((address_space(3))) void;

__device__ __forceinline__ short f2bf(float f) {
  union { float fv; unsigned u; } x; x.fv = f;
  unsigned r = x.u + 0x7FFFu + ((x.u >> 16) & 1u);
  return (short)(r >> 16);
}

__device__ __forceinline__ int cvtpk(float lo, float hi) {
  int r;
  asm("v_cvt_pk_bf16_f32 %0, %1, %2" : "=v"(r) : "v"(lo), "v"(hi));
  return r;
}

__device__ __forceinline__ facc_t mfma16(bfrag_t a, bfrag_t b, facc_t c) {
  return __builtin_amdgcn_mfma_f32_16x16x32_bf16(a, b, c, 0, 0, 0);
}
__device__ __forceinline__ f16acc_t mfma32(bfrag_t a, bfrag_t b, f16acc_t c) {
  return __builtin_amdgcn_mfma_f32_32x32x16_bf16(a, b, c, 0, 0, 0);
}

// ---- transpose weights to bf16: WT[p][e][d] = W_p[d][e] --------------------
__global__ void wt_kernel(const float* __restrict__ Wq, const float* __restrict__ Wk,
                          const float* __restrict__ Wv, short* __restrict__ WT) {
  const int p = blockIdx.x >> 4;
  const float* W = (p == 0) ? Wq : ((p == 1) ? Wk : Wv);
  short* o = WT + p * (D_ * D_);
  const int e = (blockIdx.x & 15) * 16 + (threadIdx.x >> 4);
  const int td = threadIdx.x & 15;
  #pragma unroll
  for (int dd = 0; dd < 16; ++dd) {
    int d = td * 16 + dd;
    o[e * D_ + d] = f2bf(W[d * D_ + e]);
  }
}

// ---- QKV projection: one projection per block (p = bid>>8), LDS-staged -----
// V stored transposed + slot-permuted per 32-kv group:
//   kv_local = wave*16+kch*4+r -> col (wave>>1)*32+(wave&1)*16+(kch&1)*8+(kch>>1)*4+r
__global__ __launch_bounds__(256) void proj_kernel(
    const float* __restrict__ X, const short* __restrict__ WT,
    short* __restrict__ Qb, short* __restrict__ Kb, short* __restrict__ VT) {
  __shared__ __align__(16) short Stg[256 * 72];   // 36.9 KB
  const int tid  = threadIdx.x;
  const int wave = tid >> 6, lane = tid & 63;
  const int lrow = lane & 15, kch = lane >> 4;
  const int p  = blockIdx.x >> 8;
  const int rb = blockIdx.x & 255;
  const int row0 = rb * 64 + wave * 16;
  const int arow = row0 + lrow;
  const int bblk = rb >> 6;

  bfrag_t af[8];
  #pragma unroll
  for (int kt = 0; kt < 8; ++kt) {
    const float* src = X + (size_t)arow * D_ + kt * 32 + kch * 8;
    float4 a = *reinterpret_cast<const float4*>(src);
    float4 b = *reinterpret_cast<const float4*>(src + 4);
    bfrag_t f;
    f[0] = f2bf(a.x); f[1] = f2bf(a.y); f[2] = f2bf(a.z); f[3] = f2bf(a.w);
    f[4] = f2bf(b.x); f[5] = f2bf(b.y); f[6] = f2bf(b.z); f[7] = f2bf(b.w);
    af[kt] = f;
  }

  const short* Wp = WT + p * (D_ * D_);
  facc_t acc[16];
  #pragma unroll
  for (int nt = 0; nt < 16; ++nt) acc[nt] = (facc_t)0.0f;
  #pragma unroll
  for (int kt = 0; kt < 8; ++kt) {
    #pragma unroll
    for (int nt = 0; nt < 16; ++nt) {
      bfrag_t bf = *reinterpret_cast<const bfrag_t*>(
          Wp + (nt * 16 + lrow) * D_ + kt * 32 + kch * 8);
      acc[nt] = mfma16(af[kt], bf, acc[nt]);
    }
  }
  if (p < 2) {
    const float sc = (p == 0) ? 0.0625f : 1.0f;   // fold 1/sqrt(256) into Q
    #pragma unroll
    for (int nt = 0; nt < 16; ++nt)
      #pragma unroll
      for (int r = 0; r < 4; ++r)
        Stg[(wave * 16 + kch * 4 + r) * 264 + nt * 16 + lrow] =
            f2bf(acc[nt][r] * sc);
    __syncthreads();
    short* dstbase = ((p == 0) ? Qb : Kb) + (size_t)rb * 64 * D_;
    #pragma unroll
    for (int k = 0; k < 8; ++k) {
      int c = k * 256 + tid;
      int row = c >> 5, col = c & 31;
      *reinterpret_cast<bfrag_t*>(dstbase + row * D_ + col * 8) =
          *reinterpret_cast<const bfrag_t*>(&Stg[row * 264 + col * 8]);
    }
  } else {
    #pragma unroll
    for (int nt = 0; nt < 16; ++nt) {
      s4_t v;
      #pragma unroll
      for (int r = 0; r < 4; ++r) v[r] = f2bf(acc[nt][r]);
      *reinterpret_cast<s4_t*>(
          &Stg[(nt * 16 + lrow) * 72 + (wave >> 1) * 32 + (wave & 1) * 16 +
               (kch & 1) * 8 + (kch >> 1) * 4]) = v;
    }
    __syncthreads();
    const int d = tid;
    const int s0 = (rb & 63) * 64;
    short* dst = VT + ((size_t)(bblk * D_ + d)) * S_ + s0;
    #pragma unroll
    for (int j = 0; j < 8; ++j)
      *reinterpret_cast<bfrag_t*>(dst + j * 8) =
          *reinterpret_cast<const bfrag_t*>(&Stg[d * 72 + j * 8]);
  }
}

// ---- flash attention: 4 waves x 64 q, K/V-frag reuse across 2 q-groups -----
// Swapped QK^T (32x32x16): lane owns q-rows q0+l31 (g0) and q0+32+l31 (g1).
// One K-frag read feeds both groups' MFMAs; one V-frag feeds 4 PV MFMAs.
template<int SPLIT>
__global__ __launch_bounds__(256, 1) void attn32(
    const short* __restrict__ Qb, const short* __restrict__ Kb,
    const short* __restrict__ VT, float* __restrict__ P0,
    float* __restrict__ PX, float2* __restrict__ ML) {
  // K tile [32 kv][256 d] (512B rows, byte ^= (kv&7)<<4)
  // V tile [256 d][32 slots] (64B rows, byte ^= ((d>>1)&3)<<4)
  __shared__ __align__(16) short Kl[3][32 * 256];
  __shared__ __align__(16) short Vl[3][256 * 32];
  const int tid  = threadIdx.x;
  const int wave = tid >> 6, lane = tid & 63;
  const int l31 = lane & 31, hi = lane >> 5;
  const int ksw = (lane & 7) << 4;
  const int vsw = ((l31 >> 1) & 3) << 4;
  const int hw = blockIdx.x;
  const int xcd = hw & 7, i = hw >> 3;
  int b, part, qblk;
  if constexpr (SPLIT == 4) {                     // 256 blocks
    int combo = (i & 1) * 8 + xcd;                // (b,part) pinned to XCD
    b = combo >> 2; part = combo & 3; qblk = i >> 1;
  } else if constexpr (SPLIT == 2) {              // 128 blocks
    b = xcd >> 1; part = xcd & 1; qblk = i;
  } else {                                        // 64 blocks
    b = hw >> 4; part = 0; qblk = hw & 15;
  }
  const int q0 = qblk * 256 + wave * 64;
  const int kvbase = part * (S_ / SPLIT);
  constexpr int STEPS = (S_ / SPLIT) / 32;

  const short* Kbp = Kb + (size_t)b * S_ * D_ + (size_t)kvbase * D_;
  const short* Vbp = VT + (size_t)b * D_ * S_ + kvbase;

  // Q B-operands for both q-groups: col=l31 (+32 for g1), k-slot hi*8+e
  bfrag_t qf[16], qg[16];
  const short* Qp0 = Qb + ((size_t)b * S_ + q0 + l31) * D_;
  const short* Qp1 = Qp0 + 32 * D_;
  #pragma unroll
  for (int kt = 0; kt < 16; ++kt) {
    qf[kt] = *reinterpret_cast<const bfrag_t*>(Qp0 + kt * 16 + hi * 8);
    qg[kt] = *reinterpret_cast<const bfrag_t*>(Qp1 + kt * 16 + hi * 8);
  }

  // stage one 32-kv tile (K 16KB + V 16KB): 8 x 16B DMA per thread (256 thr)
  auto stage = [&](int bf, int kv0) {
    #pragma unroll
    for (int j = 0; j < 4; ++j) {
      int L = j * 4096 + tid * 16;
      int row = L >> 9;
      int cs = (L & 511) ^ ((row & 7) << 4);
      const short* src = Kbp + (size_t)(kv0 + row) * D_ + (cs >> 1);
      short* dst = &Kl[bf][(j * 4096 + wave * 1024) >> 1];
      __builtin_amdgcn_global_load_lds((gas_v*)src, (las_v*)dst, 16, 0, 0);
    }
    #pragma unroll
    for (int j = 0; j < 4; ++j) {
      int L = j * 4096 + tid * 16;
      int d = L >> 6;
      int cs = (L & 63) ^ (((d >> 1) & 3) << 4);
      const short* src = Vbp + (size_t)d * S_ + kv0 + (cs >> 1);
      short* dst = &Vl[bf][(j * 4096 + wave * 1024) >> 1];
      __builtin_amdgcn_global_load_lds((gas_v*)src, (las_v*)dst, 16, 0, 0);
    }
  };

  f16acc_t oA[8], oB[8];
  #pragma unroll
  for (int nt = 0; nt < 8; ++nt) { oA[nt] = (f16acc_t)0.0f; oB[nt] = (f16acc_t)0.0f; }
  float mA = -3.0e38f, lA = 0.0f;
  float mB = -3.0e38f, lB = 0.0f;

  stage(0, 0);
  stage(1, 32);

  #pragma unroll 1
  for (int t = 0; t < STEPS; ++t) {
    const int buf = t % 3;
    if (t < STEPS - 1) {
      asm volatile("s_waitcnt vmcnt(8)" ::: "memory");   // own stage(t) landed
    } else {
      asm volatile("s_waitcnt vmcnt(0)" ::: "memory");
    }
    __builtin_amdgcn_sched_barrier(0);
    __builtin_amdgcn_s_barrier();
    __builtin_amdgcn_sched_barrier(0);
    if (t + 2 < STEPS) stage((t + 2) % 3, (t + 2) * 32);
    // ---- S^T = K Q^T for both q-groups: 16 kt, K-frag shared ----
    f16acc_t sA = (f16acc_t)0.0f, sB = (f16acc_t)0.0f;
    const char* Kbase = (const char*)&Kl[buf][0];
    #pragma unroll
    for (int kt = 0; kt < 16; ++kt) {
      bfrag_t kf = *reinterpret_cast<const bfrag_t*>(
          Kbase + l31 * 512 + ((kt * 32 + hi * 16) ^ ksw));
      sA = mfma32(kf, qf[kt], sA);
      sB = mfma32(kf, qg[kt], sB);
    }
    // ---- softmax g0 ----
    bfrag_t pb0, pb1, pb2, pb3;
    {
      float mx = sA[0];
      #pragma unroll
      for (int i2 = 1; i2 < 16; ++i2) mx = fmaxf(mx, sA[i2]);
      mx = fmaxf(mx, __shfl_xor(mx, 32));
      if (mx > mA + 8.0f) {
        float sf = __expf(mA - mx);
        mA = mx; lA *= sf;
        #pragma unroll
        for (int nt = 0; nt < 8; ++nt) oA[nt] *= sf;
      }
      float ls = 0.0f;
      #pragma unroll
      for (int i2 = 0; i2 < 16; ++i2) {
        float e = __expf(sA[i2] - mA);
        sA[i2] = e; ls += e;
      }
      lA += ls;
      i4_t w0, w1;
      w0.x = cvtpk(sA[0], sA[1]);   w0.y = cvtpk(sA[2], sA[3]);
      w0.z = cvtpk(sA[4], sA[5]);   w0.w = cvtpk(sA[6], sA[7]);
      w1.x = cvtpk(sA[8], sA[9]);   w1.y = cvtpk(sA[10], sA[11]);
      w1.z = cvtpk(sA[12], sA[13]); w1.w = cvtpk(sA[14], sA[15]);
      pb0 = __builtin_bit_cast(bfrag_t, w0);
      pb1 = __builtin_bit_cast(bfrag_t, w1);
    }
    // ---- softmax g1 ----
    {
      float mx = sB[0];
      #pragma unroll
      for (int i2 = 1; i2 < 16; ++i2) mx = fmaxf(mx, sB[i2]);
      mx = fmaxf(mx, __shfl_xor(mx, 32));
      if (mx > mB + 8.0f) {
        float sf = __expf(mB - mx);
        mB = mx; lB *= sf;
        #pragma unroll
        for (int nt = 0; nt < 8; ++nt) oB[nt] *= sf;
      }
      float ls = 0.0f;
      #pragma unroll
      for (int i2 = 0; i2 < 16; ++i2) {
        float e = __expf(sB[i2] - mB);
        sB[i2] = e; ls += e;
      }
      lB += ls;
      i4_t w0, w1;
      w0.x = cvtpk(sB[0], sB[1]);   w0.y = cvtpk(sB[2], sB[3]);
      w0.z = cvtpk(sB[4], sB[5]);   w0.w = cvtpk(sB[6], sB[7]);
      w1.x = cvtpk(sB[8], sB[9]);   w1.y = cvtpk(sB[10], sB[11]);
      w1.z = cvtpk(sB[12], sB[13]); w1.w = cvtpk(sB[14], sB[15]);
      pb2 = __builtin_bit_cast(bfrag_t, w0);
      pb3 = __builtin_bit_cast(bfrag_t, w1);
    }
    // ---- O^T += V^T P^T : V-frag shared across 4 MFMAs ----
    const char* Vbase = (const char*)&Vl[buf][0];
    #pragma unroll
    for (int nt = 0; nt < 8; ++nt) {
      const char* vb = Vbase + (nt * 32 + l31) * 64;
      bfrag_t v0 = *reinterpret_cast<const bfrag_t*>(vb + ((hi * 16) ^ vsw));
      bfrag_t v1 = *reinterpret_cast<const bfrag_t*>(vb + ((32 + hi * 16) ^ vsw));
      oA[nt] = mfma32(v0, pb0, oA[nt]);
      oA[nt] = mfma32(v1, pb1, oA[nt]);
      oB[nt] = mfma32(v0, pb2, oB[nt]);
      oB[nt] = mfma32(v1, pb3, oB[nt]);
    }
  }

  // ---- epilogue ----
  lA += __shfl_xor(lA, 32);
  lB += __shfl_xor(lB, 32);
  float* Pd = (SPLIT == 1 || part == 0)
                  ? P0 : PX + (size_t)(part - 1) * ((size_t)B_ * S_ * D_);
  float* Og0 = Pd + ((size_t)b * S_ + q0 + l31) * D_;
  float* Og1 = Og0 + 32 * D_;
  if constexpr (SPLIT == 1) {
    float ivA = 1.0f / lA, ivB = 1.0f / lB;
    #pragma unroll
    for (int nt = 0; nt < 8; ++nt)
      #pragma unroll
      for (int gg = 0; gg < 4; ++gg) {
        float4 o;
        o.x = oA[nt][gg * 4 + 0] * ivA; o.y = oA[nt][gg * 4 + 1] * ivA;
        o.z = oA[nt][gg * 4 + 2] * ivA; o.w = oA[nt][gg * 4 + 3] * ivA;
        *reinterpret_cast<float4*>(Og0 + nt * 32 + hi * 4 + gg * 8) = o;
        o.x = oB[nt][gg * 4 + 0] * ivB; o.y = oB[nt][gg * 4 + 1] * ivB;
        o.z = oB[nt][gg * 4 + 2] * ivB; o.w = oB[nt][gg * 4 + 3] * ivB;
        *reinterpret_cast<float4*>(Og1 + nt * 32 + hi * 4 + gg * 8) = o;
      }
  } else {
    #pragma unroll
    for (int nt = 0; nt < 8; ++nt)
      #pragma unroll
      for (int gg = 0; gg < 4; ++gg) {
        float4 o;
        o.x = oA[nt][gg * 4 + 0]; o.y = oA[nt][gg * 4 + 1];
        o.z = oA[nt][gg * 4 + 2]; o.w = oA[nt][gg * 4 + 3];
        *reinterpret_cast<float4*>(Og0 + nt * 32 + hi * 4 + gg * 8) = o;
        o.x = oB[nt][gg * 4 + 0]; o.y = oB[nt][gg * 4 + 1];
        o.z = oB[nt][gg * 4 + 2]; o.w = oB[nt][gg * 4 + 3];
        *reinterpret_cast<float4*>(Og1 + nt * 32 + hi * 4 + gg * 8) = o;
      }
    if (lane < 32) {
      float2 ml0; ml0.x = mA; ml0.y = lA;
      ML[part * (B_ * S_) + b * S_ + q0 + l31] = ml0;
      float2 ml1; ml1.x = mB; ml1.y = lB;
      ML[part * (B_ * S_) + b * S_ + q0 + 32 + l31] = ml1;
    }
  }
}

// ---- combine SPLIT kv-part partials ----------------------------------------
template<int SPLIT>
__global__ __launch_bounds__(256) void combineN(
    const float* __restrict__ PX, const float2* __restrict__ ML,
    float* __restrict__ Out) {
  const int r = blockIdx.x * 4 + (threadIdx.x >> 6);
  const int d4 = (threadIdx.x & 63) * 4;
  float2 ml[SPLIT];
  #pragma unroll
  for (int p = 0; p < SPLIT; ++p) ml[p] = ML[p * (B_ * S_) + r];
  float m = ml[0].x;
  #pragma unroll
  for (int p = 1; p < SPLIT; ++p) m = fmaxf(m, ml[p].x);
  float w[SPLIT];
  float denom = 0.0f;
  #pragma unroll
  for (int p = 0; p < SPLIT; ++p) {
    w[p] = __expf(ml[p].x - m);
    denom += ml[p].y * w[p];
  }
  float inv = 1.0f / denom;
  size_t idx = (size_t)r * D_ + d4;
  float4 x = *reinterpret_cast<float4*>(Out + idx);
  float4 acc;
  acc.x = x.x * w[0]; acc.y = x.y * w[0]; acc.z = x.z * w[0]; acc.w = x.w * w[0];
  #pragma unroll
  for (int p = 1; p < SPLIT; ++p) {
    float4 y = *reinterpret_cast<const float4*>(
        PX + (size_t)(p - 1) * ((size_t)B_ * S_ * D_) + idx);
    acc.x += y.x * w[p]; acc.y += y.y * w[p];
    acc.z += y.z * w[p]; acc.w += y.w * w[p];
  }
  acc.x *= inv; acc.y *= inv; acc.z *= inv; acc.w *= inv;
  *reinterpret_cast<float4*>(Out + idx) = acc;
}

extern "C" void kernel_launch(void* const* d_in, const int* in_sizes, int n_in,
                              void* d_out, int out_size, void* d_ws, size_t ws_size,
                              hipStream_t stream) {
  const float* X  = (const float*)d_in[0];
  const float* Wq = (const float*)d_in[1];
  const float* Wk = (const float*)d_in[2];
  const float* Wv = (const float*)d_in[3];
  float* out = (float*)d_out;

  char* ws = (char*)d_ws;
  short* Qb = (short*)(ws);                       // 8 MB
  short* Kb = (short*)(ws + 8388608);             // 8 MB
  short* VT = (short*)(ws + 16777216);            // 8 MB (V^T, slot-permuted)
  short* WT = (short*)(ws + 25165824);            // 384 KB
  float2* ML = (float2*)(ws + 25690112);          // 512 KB (m,l per part)
  float* PX  = (float*)(ws + 26214400);           // up to 3 x 16 MB partials
  const size_t NP = (size_t)B_ * S_ * D_ * 4;
  const size_t need4 = 26214400 + 3 * NP;
  const size_t need2 = 26214400 + 1 * NP;

  wt_kernel<<<48, 256, 0, stream>>>(Wq, Wk, Wv, WT);
  proj_kernel<<<768, 256, 0, stream>>>(X, WT, Qb, Kb, VT);
  if (ws_size >= need4) {
    attn32<4><<<256, 256, 0, stream>>>(Qb, Kb, VT, out, PX, ML);
    combineN<4><<<(B_ * S_) / 4, 256, 0, stream>>>(PX, ML, out);
  } else if (ws_size >= need2) {
    attn32<2><<<128, 256, 0, stream>>>(Qb, Kb, VT, out, PX, ML);
    combineN<2><<<(B_ * S_) / 4, 256, 0, stream>>>(PX, ML, out);
  } else {
    attn32<1><<<64, 256, 0, stream>>>(Qb, Kb, VT, out, PX, (float2*)out);
  }
}

// Round 12
// 158.239 us; speedup vs baseline: 3.6573x; 3.6573x over previous
//
#include <hip/hip_runtime.h>
#include <hip/hip_bf16.h>

typedef __attribute__((ext_vector_type(8))) short bfrag_t;
typedef __attribute__((ext_vector_type(4))) short s4_t;
typedef __attribute__((ext_vector_type(4))) float facc_t;
typedef __attribute__((ext_vector_type(16))) float f16acc_t;
typedef __attribute__((ext_vector_type(4))) int i4_t;

#define B_ 4
#define S_ 4096
#define D_ 256

using gas_v = const __attribute__((address_space(1))) void;
using las_v = __attribute__((address_space(3))) void;

__device__ __forceinline__ short f2bf(float f) {
  union { float fv; unsigned u; } x; x.fv = f;
  unsigned r = x.u + 0x7FFFu + ((x.u >> 16) & 1u);
  return (short)(r >> 16);
}

__device__ __forceinline__ int cvtpk(float lo, float hi) {
  int r;
  asm("v_cvt_pk_bf16_f32 %0, %1, %2" : "=v"(r) : "v"(lo), "v"(hi));
  return r;
}

__device__ __forceinline__ facc_t mfma16(bfrag_t a, bfrag_t b, facc_t c) {
  return __builtin_amdgcn_mfma_f32_16x16x32_bf16(a, b, c, 0, 0, 0);
}
__device__ __forceinline__ f16acc_t mfma32(bfrag_t a, bfrag_t b, f16acc_t c) {
  return __builtin_amdgcn_mfma_f32_32x32x16_bf16(a, b, c, 0, 0, 0);
}

// ---- transpose weights to bf16: WT[p][e][d] = W_p[d][e] --------------------
__global__ void wt_kernel(const float* __restrict__ Wq, const float* __restrict__ Wk,
                          const float* __restrict__ Wv, short* __restrict__ WT) {
  const int p = blockIdx.x >> 4;
  const float* W = (p == 0) ? Wq : ((p == 1) ? Wk : Wv);
  short* o = WT + p * (D_ * D_);
  const int e = (blockIdx.x & 15) * 16 + (threadIdx.x >> 4);
  const int td = threadIdx.x & 15;
  #pragma unroll
  for (int dd = 0; dd < 16; ++dd) {
    int d = td * 16 + dd;
    o[e * D_ + d] = f2bf(W[d * D_ + e]);
  }
}

// ---- QKV projection: one projection per block (p = bid>>8), LDS-staged -----
// V stored transposed + slot-permuted per 32-kv group:
//   kv_local = wave*16+kch*4+r -> col (wave>>1)*32+(wave&1)*16+(kch&1)*8+(kch>>1)*4+r
__global__ __launch_bounds__(256) void proj_kernel(
    const float* __restrict__ X, const short* __restrict__ WT,
    short* __restrict__ Qb, short* __restrict__ Kb, short* __restrict__ VT) {
  __shared__ __align__(16) short Stg[256 * 72];   // 36.9 KB
  const int tid  = threadIdx.x;
  const int wave = tid >> 6, lane = tid & 63;
  const int lrow = lane & 15, kch = lane >> 4;
  const int p  = blockIdx.x >> 8;
  const int rb = blockIdx.x & 255;
  const int row0 = rb * 64 + wave * 16;
  const int arow = row0 + lrow;
  const int bblk = rb >> 6;

  bfrag_t af[8];
  #pragma unroll
  for (int kt = 0; kt < 8; ++kt) {
    const float* src = X + (size_t)arow * D_ + kt * 32 + kch * 8;
    float4 a = *reinterpret_cast<const float4*>(src);
    float4 b = *reinterpret_cast<const float4*>(src + 4);
    bfrag_t f;
    f[0] = f2bf(a.x); f[1] = f2bf(a.y); f[2] = f2bf(a.z); f[3] = f2bf(a.w);
    f[4] = f2bf(b.x); f[5] = f2bf(b.y); f[6] = f2bf(b.z); f[7] = f2bf(b.w);
    af[kt] = f;
  }

  const short* Wp = WT + p * (D_ * D_);
  facc_t acc[16];
  #pragma unroll
  for (int nt = 0; nt < 16; ++nt) acc[nt] = (facc_t)0.0f;
  #pragma unroll
  for (int kt = 0; kt < 8; ++kt) {
    #pragma unroll
    for (int nt = 0; nt < 16; ++nt) {
      bfrag_t bf = *reinterpret_cast<const bfrag_t*>(
          Wp + (nt * 16 + lrow) * D_ + kt * 32 + kch * 8);
      acc[nt] = mfma16(af[kt], bf, acc[nt]);
    }
  }
  if (p < 2) {
    const float sc = (p == 0) ? 0.0625f : 1.0f;   // fold 1/sqrt(256) into Q
    #pragma unroll
    for (int nt = 0; nt < 16; ++nt)
      #pragma unroll
      for (int r = 0; r < 4; ++r)
        Stg[(wave * 16 + kch * 4 + r) * 264 + nt * 16 + lrow] =
            f2bf(acc[nt][r] * sc);
    __syncthreads();
    short* dstbase = ((p == 0) ? Qb : Kb) + (size_t)rb * 64 * D_;
    #pragma unroll
    for (int k = 0; k < 8; ++k) {
      int c = k * 256 + tid;
      int row = c >> 5, col = c & 31;
      *reinterpret_cast<bfrag_t*>(dstbase + row * D_ + col * 8) =
          *reinterpret_cast<const bfrag_t*>(&Stg[row * 264 + col * 8]);
    }
  } else {
    #pragma unroll
    for (int nt = 0; nt < 16; ++nt) {
      s4_t v;
      #pragma unroll
      for (int r = 0; r < 4; ++r) v[r] = f2bf(acc[nt][r]);
      *reinterpret_cast<s4_t*>(
          &Stg[(nt * 16 + lrow) * 72 + (wave >> 1) * 32 + (wave & 1) * 16 +
               (kch & 1) * 8 + (kch >> 1) * 4]) = v;
    }
    __syncthreads();
    const int d = tid;
    const int s0 = (rb & 63) * 64;
    short* dst = VT + ((size_t)(bblk * D_ + d)) * S_ + s0;
    #pragma unroll
    for (int j = 0; j < 8; ++j)
      *reinterpret_cast<bfrag_t*>(dst + j * 8) =
          *reinterpret_cast<const bfrag_t*>(&Stg[d * 72 + j * 8]);
  }
}

// ---- flash attention, 32 q/wave via 32x32x16 MFMA, kv-split template -------
// Swapped QK^T: S^T col=lane&31=q, row=kv=(reg&3)+8*(reg>>2)+4*hi.
// P regs feed PV B-operand directly; V slot-permuted so A-frag is one b128.
template<int SPLIT>
__global__ __launch_bounds__(256, 2) void attn32(
    const short* __restrict__ Qb, const short* __restrict__ Kb,
    const short* __restrict__ VT, float* __restrict__ P0,
    float* __restrict__ PX, float2* __restrict__ ML) {
  // K tile [32 kv][256 d] (512B rows, byte ^= (kv&7)<<4)
  // V tile [256 d][32 slots] (64B rows, byte ^= ((d>>1)&3)<<4)
  __shared__ __align__(16) short Kl[2][32 * 256];
  __shared__ __align__(16) short Vl[2][256 * 32];
  const int tid  = threadIdx.x;
  const int wave = tid >> 6, lane = tid & 63;
  const int l31 = lane & 31, hi = lane >> 5;
  const int ksw = (lane & 7) << 4;
  const int vsw = ((l31 >> 1) & 3) << 4;
  const int hw = blockIdx.x;
  const int g = hw & 7, rest = hw >> 3;
  int b, part, qblk;
  if constexpr (SPLIT == 4)      { b = g >> 1; part = (g & 1) * 2 + (rest & 1); qblk = rest >> 1; }
  else if constexpr (SPLIT == 2) { b = g >> 1; part = g & 1;                    qblk = rest; }
  else                           { b = g >> 1; part = 0;                qblk = (g & 1) * 16 + rest; }
  const int q0 = qblk * 128 + wave * 32;
  const int kvbase = part * (S_ / SPLIT);
  constexpr int STEPS = (S_ / SPLIT) / 32;

  const short* Kbp = Kb + (size_t)b * S_ * D_ + (size_t)kvbase * D_;
  const short* Vbp = VT + (size_t)b * D_ * S_ + kvbase;

  // Q as B-operand: col = l31 (q), k-slot hi*8+e -> d = kt*16 + hi*8 + e
  bfrag_t qf[16];
  const short* Qp = Qb + ((size_t)b * S_ + q0 + l31) * D_;
  #pragma unroll
  for (int kt = 0; kt < 16; ++kt)
    qf[kt] = *reinterpret_cast<const bfrag_t*>(Qp + kt * 16 + hi * 8);

  auto stage = [&](int bf, int kv0) {
    #pragma unroll
    for (int j = 0; j < 4; ++j) {           // K 16 KB
      int L = j * 4096 + tid * 16;
      int row = L >> 9;
      int cs = (L & 511) ^ ((row & 7) << 4);
      const short* src = Kbp + (size_t)(kv0 + row) * D_ + (cs >> 1);
      short* dst = &Kl[bf][(j * 4096 + wave * 1024) >> 1];
      __builtin_amdgcn_global_load_lds((gas_v*)src, (las_v*)dst, 16, 0, 0);
    }
    #pragma unroll
    for (int j = 0; j < 4; ++j) {           // V 16 KB
      int L = j * 4096 + tid * 16;
      int d = L >> 6;
      int cs = (L & 63) ^ (((d >> 1) & 3) << 4);
      const short* src = Vbp + (size_t)d * S_ + kv0 + (cs >> 1);
      short* dst = &Vl[bf][(j * 4096 + wave * 1024) >> 1];
      __builtin_amdgcn_global_load_lds((gas_v*)src, (las_v*)dst, 16, 0, 0);
    }
  };

  f16acc_t o32[8];
  #pragma unroll
  for (int nt = 0; nt < 8; ++nt) o32[nt] = (f16acc_t)0.0f;
  float mrow = -3.0e38f, lsum = 0.0f;

  stage(0, 0);
  asm volatile("s_waitcnt vmcnt(0)" ::: "memory");
  __syncthreads();
  int buf = 0;

  #pragma unroll 1
  for (int t = 0; t < STEPS; ++t) {
    if (t < STEPS - 1) stage(buf ^ 1, (t + 1) * 32);
    // ---- S^T = K Q^T : 16 kt of 32x32x16 ----
    f16acc_t s16 = (f16acc_t)0.0f;
    const char* Kbase = (const char*)&Kl[buf][0];
    __builtin_amdgcn_s_setprio(1);
    #pragma unroll
    for (int kt = 0; kt < 16; ++kt) {
      bfrag_t kf = *reinterpret_cast<const bfrag_t*>(
          Kbase + l31 * 512 + ((kt * 32 + hi * 16) ^ ksw));
      s16 = mfma32(kf, qf[kt], s16);
    }
    __builtin_amdgcn_s_setprio(0);
    // ---- softmax: lane owns q = q0+l31; 16 kv in regs; one shfl ----
    float mx = s16[0];
    #pragma unroll
    for (int i = 1; i < 16; ++i) mx = fmaxf(mx, s16[i]);
    mx = fmaxf(mx, __shfl_xor(mx, 32));
    if (mx > mrow + 8.0f) {                 // defer-max rescale
      float sf = __expf(mrow - mx);
      mrow = mx;
      lsum *= sf;
      #pragma unroll
      for (int nt = 0; nt < 8; ++nt) o32[nt] *= sf;
    }
    float pe[16];
    float ls = 0.0f;
    #pragma unroll
    for (int i = 0; i < 16; ++i) {
      pe[i] = __expf(s16[i] - mrow);
      ls += pe[i];
    }
    lsum += ls;
    // ---- P -> bf16 B-frags (register-order; cvt_pk pairs) ----
    i4_t w0, w1;
    w0.x = cvtpk(pe[0], pe[1]);  w0.y = cvtpk(pe[2], pe[3]);
    w0.z = cvtpk(pe[4], pe[5]);  w0.w = cvtpk(pe[6], pe[7]);
    w1.x = cvtpk(pe[8], pe[9]);  w1.y = cvtpk(pe[10], pe[11]);
    w1.z = cvtpk(pe[12], pe[13]); w1.w = cvtpk(pe[14], pe[15]);
    bfrag_t pb0 = __builtin_bit_cast(bfrag_t, w0);
    bfrag_t pb1 = __builtin_bit_cast(bfrag_t, w1);
    // ---- O^T += V^T P^T : 8 d-blocks x 2 ----
    const char* Vbase = (const char*)&Vl[buf][0];
    __builtin_amdgcn_s_setprio(1);
    #pragma unroll
    for (int nt = 0; nt < 8; ++nt) {
      const char* vb = Vbase + (nt * 32 + l31) * 64;
      bfrag_t v0 = *reinterpret_cast<const bfrag_t*>(vb + ((hi * 16) ^ vsw));
      o32[nt] = mfma32(v0, pb0, o32[nt]);
      bfrag_t v1 = *reinterpret_cast<const bfrag_t*>(vb + ((32 + hi * 16) ^ vsw));
      o32[nt] = mfma32(v1, pb1, o32[nt]);
    }
    __builtin_amdgcn_s_setprio(0);
    asm volatile("s_waitcnt vmcnt(0)" ::: "memory");
    __syncthreads();
    buf ^= 1;
  }

  // ---- epilogue ----
  lsum += __shfl_xor(lsum, 32);
  float* Pd = (SPLIT == 1 || part == 0)
                  ? P0 : PX + (size_t)(part - 1) * ((size_t)B_ * S_ * D_);
  float* Og = Pd + ((size_t)b * S_ + q0 + l31) * D_;
  if constexpr (SPLIT == 1) {
    float inv = 1.0f / lsum;
    #pragma unroll
    for (int nt = 0; nt < 8; ++nt)
      #pragma unroll
      for (int gg = 0; gg < 4; ++gg) {
        float4 o;
        o.x = o32[nt][gg * 4 + 0] * inv; o.y = o32[nt][gg * 4 + 1] * inv;
        o.z = o32[nt][gg * 4 + 2] * inv; o.w = o32[nt][gg * 4 + 3] * inv;
        *reinterpret_cast<float4*>(Og + nt * 32 + hi * 4 + gg * 8) = o;
      }
  } else {
    #pragma unroll
    for (int nt = 0; nt < 8; ++nt)
      #pragma unroll
      for (int gg = 0; gg < 4; ++gg) {
        float4 o;
        o.x = o32[nt][gg * 4 + 0]; o.y = o32[nt][gg * 4 + 1];
        o.z = o32[nt][gg * 4 + 2]; o.w = o32[nt][gg * 4 + 3];
        *reinterpret_cast<float4*>(Og + nt * 32 + hi * 4 + gg * 8) = o;
      }
    if (lane < 32) {
      float2 ml; ml.x = mrow; ml.y = lsum;
      ML[part * (B_ * S_) + b * S_ + q0 + l31] = ml;
    }
  }
}

// ---- combine SPLIT kv-part partials ----------------------------------------
template<int SPLIT>
__global__ __launch_bounds__(256) void combineN(
    const float* __restrict__ PX, const float2* __restrict__ ML,
    float* __restrict__ Out) {
  const int r = blockIdx.x * 4 + (threadIdx.x >> 6);
  const int d4 = (threadIdx.x & 63) * 4;
  float2 ml[SPLIT];
  #pragma unroll
  for (int p = 0; p < SPLIT; ++p) ml[p] = ML[p * (B_ * S_) + r];
  float m = ml[0].x;
  #pragma unroll
  for (int p = 1; p < SPLIT; ++p) m = fmaxf(m, ml[p].x);
  float w[SPLIT];
  float denom = 0.0f;
  #pragma unroll
  for (int p = 0; p < SPLIT; ++p) {
    w[p] = __expf(ml[p].x - m);
    denom += ml[p].y * w[p];
  }
  float inv = 1.0f / denom;
  size_t idx = (size_t)r * D_ + d4;
  float4 x = *reinterpret_cast<float4*>(Out + idx);
  float4 acc;
  acc.x = x.x * w[0]; acc.y = x.y * w[0]; acc.z = x.z * w[0]; acc.w = x.w * w[0];
  #pragma unroll
  for (int p = 1; p < SPLIT; ++p) {
    float4 y = *reinterpret_cast<const float4*>(
        PX + (size_t)(p - 1) * ((size_t)B_ * S_ * D_) + idx);
    acc.x += y.x * w[p]; acc.y += y.y * w[p];
    acc.z += y.z * w[p]; acc.w += y.w * w[p];
  }
  acc.x *= inv; acc.y *= inv; acc.z *= inv; acc.w *= inv;
  *reinterpret_cast<float4*>(Out + idx) = acc;
}

extern "C" void kernel_launch(void* const* d_in, const int* in_sizes, int n_in,
                              void* d_out, int out_size, void* d_ws, size_t ws_size,
                              hipStream_t stream) {
  const float* X  = (const float*)d_in[0];
  const float* Wq = (const float*)d_in[1];
  const float* Wk = (const float*)d_in[2];
  const float* Wv = (const float*)d_in[3];
  float* out = (float*)d_out;

  char* ws = (char*)d_ws;
  short* Qb = (short*)(ws);                       // 8 MB
  short* Kb = (short*)(ws + 8388608);             // 8 MB
  short* VT = (short*)(ws + 16777216);            // 8 MB (V^T, slot-permuted)
  short* WT = (short*)(ws + 25165824);            // 384 KB
  float2* ML = (float2*)(ws + 25690112);          // 512 KB (m,l per part)
  float* PX  = (float*)(ws + 26214400);           // up to 3 x 16 MB partials
  const size_t NP = (size_t)B_ * S_ * D_ * 4;
  const size_t need4 = 26214400 + 3 * NP;
  const size_t need2 = 26214400 + 1 * NP;

  wt_kernel<<<48, 256, 0, stream>>>(Wq, Wk, Wv, WT);
  proj_kernel<<<768, 256, 0, stream>>>(X, WT, Qb, Kb, VT);
  if (ws_size >= need4) {
    attn32<4><<<512, 256, 0, stream>>>(Qb, Kb, VT, out, PX, ML);
    combineN<4><<<(B_ * S_) / 4, 256, 0, stream>>>(PX, ML, out);
  } else if (ws_size >= need2) {
    attn32<2><<<256, 256, 0, stream>>>(Qb, Kb, VT, out, PX, ML);
    combineN<2><<<(B_ * S_) / 4, 256, 0, stream>>>(PX, ML, out);
  } else {
    attn32<1><<<128, 256, 0, stream>>>(Qb, Kb, VT, out, PX, (float2*)out);
  }
}

// Round 13
// 158.190 us; speedup vs baseline: 3.6585x; 1.0003x over previous
//
#include <hip/hip_runtime.h>
#include <hip/hip_bf16.h>

typedef __attribute__((ext_vector_type(8))) short bfrag_t;
typedef __attribute__((ext_vector_type(4))) short s4_t;
typedef __attribute__((ext_vector_type(4))) float facc_t;
typedef __attribute__((ext_vector_type(16))) float f16acc_t;
typedef __attribute__((ext_vector_type(4))) int i4_t;

#define B_ 4
#define S_ 4096
#define D_ 256

using gas_v = const __attribute__((address_space(1))) void;
using las_v = __attribute__((address_space(3))) void;

__device__ __forceinline__ short f2bf(float f) {
  union { float fv; unsigned u; } x; x.fv = f;
  unsigned r = x.u + 0x7FFFu + ((x.u >> 16) & 1u);
  return (short)(r >> 16);
}

__device__ __forceinline__ int cvtpk(float lo, float hi) {
  int r;
  asm("v_cvt_pk_bf16_f32 %0, %1, %2" : "=v"(r) : "v"(lo), "v"(hi));
  return r;
}

// 2^x via v_exp_f32 (softmax computed in base-2 domain; Q pre-scaled by log2e)
__device__ __forceinline__ float fexp2(float x) {
  float r;
  asm("v_exp_f32 %0, %1" : "=v"(r) : "v"(x));
  return r;
}

__device__ __forceinline__ facc_t mfma16(bfrag_t a, bfrag_t b, facc_t c) {
  return __builtin_amdgcn_mfma_f32_16x16x32_bf16(a, b, c, 0, 0, 0);
}
__device__ __forceinline__ f16acc_t mfma32(bfrag_t a, bfrag_t b, f16acc_t c) {
  return __builtin_amdgcn_mfma_f32_32x32x16_bf16(a, b, c, 0, 0, 0);
}

// ---- transpose weights to bf16 via LDS tiles: WT[p][e][d] = W_p[d][e] ------
// grid 12: p = b>>2, e-stripe = (b&3)*64. Coalesced on both sides.
__global__ __launch_bounds__(256) void wt_kernel(
    const float* __restrict__ Wq, const float* __restrict__ Wk,
    const float* __restrict__ Wv, short* __restrict__ WT) {
  __shared__ short Tl[256 * 68];                  // [d][e_local], pad 68
  const int p = blockIdx.x >> 2;
  const int estripe = (blockIdx.x & 3) * 64;
  const float* W = (p == 0) ? Wq : ((p == 1) ? Wk : Wv);
  short* o = WT + p * (D_ * D_);
  const int el = threadIdx.x & 63, dq = threadIdx.x >> 6;
  #pragma unroll 16
  for (int pass = 0; pass < 64; ++pass) {
    int d = pass * 4 + dq;
    Tl[d * 68 + el] = f2bf(W[d * 256 + estripe + el]);   // coalesced 256B/wave
  }
  __syncthreads();
  const int eo = threadIdx.x >> 2, qd = threadIdx.x & 3;
  #pragma unroll
  for (int j = 0; j < 8; ++j) {
    s4_t a, b2;
    #pragma unroll
    for (int t2 = 0; t2 < 4; ++t2) a[t2]  = Tl[(qd * 64 + j * 8 + t2) * 68 + eo];
    #pragma unroll
    for (int t2 = 0; t2 < 4; ++t2) b2[t2] = Tl[(qd * 64 + j * 8 + 4 + t2) * 68 + eo];
    short* dst = o + (estripe + eo) * 256 + qd * 64 + j * 8;
    *reinterpret_cast<s4_t*>(dst) = a;              // per-thread 128B contiguous
    *reinterpret_cast<s4_t*>(dst + 4) = b2;
  }
}

// ---- QKV projection: one projection per block (p = bid>>8), LDS-staged -----
// Q pre-scaled by (1/sqrt(256)) * log2(e) for base-2 softmax.
// V stored transposed + slot-permuted per 32-kv group:
//   kv_local = wave*16+kch*4+r -> col (wave>>1)*32+(wave&1)*16+(kch&1)*8+(kch>>1)*4+r
__global__ __launch_bounds__(256) void proj_kernel(
    const float* __restrict__ X, const short* __restrict__ WT,
    short* __restrict__ Qb, short* __restrict__ Kb, short* __restrict__ VT) {
  __shared__ __align__(16) short Stg[256 * 72];   // 36.9 KB
  const int tid  = threadIdx.x;
  const int wave = tid >> 6, lane = tid & 63;
  const int lrow = lane & 15, kch = lane >> 4;
  const int p  = blockIdx.x >> 8;
  const int rb = blockIdx.x & 255;
  const int row0 = rb * 64 + wave * 16;
  const int arow = row0 + lrow;
  const int bblk = rb >> 6;

  bfrag_t af[8];
  #pragma unroll
  for (int kt = 0; kt < 8; ++kt) {
    const float* src = X + (size_t)arow * D_ + kt * 32 + kch * 8;
    float4 a = *reinterpret_cast<const float4*>(src);
    float4 b = *reinterpret_cast<const float4*>(src + 4);
    bfrag_t f;
    f[0] = f2bf(a.x); f[1] = f2bf(a.y); f[2] = f2bf(a.z); f[3] = f2bf(a.w);
    f[4] = f2bf(b.x); f[5] = f2bf(b.y); f[6] = f2bf(b.z); f[7] = f2bf(b.w);
    af[kt] = f;
  }

  const short* Wp = WT + p * (D_ * D_);
  facc_t acc[16];
  #pragma unroll
  for (int nt = 0; nt < 16; ++nt) acc[nt] = (facc_t)0.0f;
  #pragma unroll
  for (int kt = 0; kt < 8; ++kt) {
    #pragma unroll
    for (int nt = 0; nt < 16; ++nt) {
      bfrag_t bf = *reinterpret_cast<const bfrag_t*>(
          Wp + (nt * 16 + lrow) * D_ + kt * 32 + kch * 8);
      acc[nt] = mfma16(af[kt], bf, acc[nt]);
    }
  }
  if (p < 2) {
    // Q: 0.0625 * log2(e) = 0.09016844; K: 1.0
    const float sc = (p == 0) ? 0.09016844f : 1.0f;
    #pragma unroll
    for (int nt = 0; nt < 16; ++nt)
      #pragma unroll
      for (int r = 0; r < 4; ++r)
        Stg[(wave * 16 + kch * 4 + r) * 264 + nt * 16 + lrow] =
            f2bf(acc[nt][r] * sc);
    __syncthreads();
    short* dstbase = ((p == 0) ? Qb : Kb) + (size_t)rb * 64 * D_;
    #pragma unroll
    for (int k = 0; k < 8; ++k) {
      int c = k * 256 + tid;
      int row = c >> 5, col = c & 31;
      *reinterpret_cast<bfrag_t*>(dstbase + row * D_ + col * 8) =
          *reinterpret_cast<const bfrag_t*>(&Stg[row * 264 + col * 8]);
    }
  } else {
    #pragma unroll
    for (int nt = 0; nt < 16; ++nt) {
      s4_t v;
      #pragma unroll
      for (int r = 0; r < 4; ++r) v[r] = f2bf(acc[nt][r]);
      *reinterpret_cast<s4_t*>(
          &Stg[(nt * 16 + lrow) * 72 + (wave >> 1) * 32 + (wave & 1) * 16 +
               (kch & 1) * 8 + (kch >> 1) * 4]) = v;
    }
    __syncthreads();
    const int d = tid;
    const int s0 = (rb & 63) * 64;
    short* dst = VT + ((size_t)(bblk * D_ + d)) * S_ + s0;
    #pragma unroll
    for (int j = 0; j < 8; ++j)
      *reinterpret_cast<bfrag_t*>(dst + j * 8) =
          *reinterpret_cast<const bfrag_t*>(&Stg[d * 72 + j * 8]);
  }
}

// ---- flash attention, 32 q/wave via 32x32x16 MFMA, kv-split template -------
// Swapped QK^T: S^T col=lane&31=q, row=kv=(reg&3)+8*(reg>>2)+4*hi.
// Base-2 online softmax (Q pre-scaled by log2e). P regs feed PV B directly.
template<int SPLIT>
__global__ __launch_bounds__(256, 2) void attn32(
    const short* __restrict__ Qb, const short* __restrict__ Kb,
    const short* __restrict__ VT, float* __restrict__ P0,
    float* __restrict__ PX, float2* __restrict__ ML) {
  // K tile [32 kv][256 d] (512B rows, byte ^= (kv&7)<<4)
  // V tile [256 d][32 slots] (64B rows, byte ^= ((d>>1)&3)<<4)
  __shared__ __align__(16) short Kl[2][32 * 256];
  __shared__ __align__(16) short Vl[2][256 * 32];
  const int tid  = threadIdx.x;
  const int wave = tid >> 6, lane = tid & 63;
  const int l31 = lane & 31, hi = lane >> 5;
  const int ksw = (lane & 7) << 4;
  const int vsw = ((l31 >> 1) & 3) << 4;
  const int hw = blockIdx.x;
  const int g = hw & 7, rest = hw >> 3;
  int b, part, qblk;
  if constexpr (SPLIT == 4)      { b = g >> 1; part = (g & 1) * 2 + (rest & 1); qblk = rest >> 1; }
  else if constexpr (SPLIT == 2) { b = g >> 1; part = g & 1;                    qblk = rest; }
  else                           { b = g >> 1; part = 0;                qblk = (g & 1) * 16 + rest; }
  const int q0 = qblk * 128 + wave * 32;
  const int kvbase = part * (S_ / SPLIT);
  constexpr int STEPS = (S_ / SPLIT) / 32;

  const short* Kbp = Kb + (size_t)b * S_ * D_ + (size_t)kvbase * D_;
  const short* Vbp = VT + (size_t)b * D_ * S_ + kvbase;

  // Q as B-operand: col = l31 (q), k-slot hi*8+e -> d = kt*16 + hi*8 + e
  bfrag_t qf[16];
  const short* Qp = Qb + ((size_t)b * S_ + q0 + l31) * D_;
  #pragma unroll
  for (int kt = 0; kt < 16; ++kt)
    qf[kt] = *reinterpret_cast<const bfrag_t*>(Qp + kt * 16 + hi * 8);

  auto stage = [&](int bf, int kv0) {
    #pragma unroll
    for (int j = 0; j < 4; ++j) {           // K 16 KB
      int L = j * 4096 + tid * 16;
      int row = L >> 9;
      int cs = (L & 511) ^ ((row & 7) << 4);
      const short* src = Kbp + (size_t)(kv0 + row) * D_ + (cs >> 1);
      short* dst = &Kl[bf][(j * 4096 + wave * 1024) >> 1];
      __builtin_amdgcn_global_load_lds((gas_v*)src, (las_v*)dst, 16, 0, 0);
    }
    #pragma unroll
    for (int j = 0; j < 4; ++j) {           // V 16 KB
      int L = j * 4096 + tid * 16;
      int d = L >> 6;
      int cs = (L & 63) ^ (((d >> 1) & 3) << 4);
      const short* src = Vbp + (size_t)d * S_ + kv0 + (cs >> 1);
      short* dst = &Vl[bf][(j * 4096 + wave * 1024) >> 1];
      __builtin_amdgcn_global_load_lds((gas_v*)src, (las_v*)dst, 16, 0, 0);
    }
  };

  f16acc_t o32[8];
  #pragma unroll
  for (int nt = 0; nt < 8; ++nt) o32[nt] = (f16acc_t)0.0f;
  float mrow = -3.0e38f, lsum = 0.0f;

  stage(0, 0);
  asm volatile("s_waitcnt vmcnt(0)" ::: "memory");
  __syncthreads();
  int buf = 0;

  #pragma unroll 1
  for (int t = 0; t < STEPS; ++t) {
    if (t < STEPS - 1) stage(buf ^ 1, (t + 1) * 32);
    // ---- S^T = K Q^T : 16 kt of 32x32x16 ----
    f16acc_t s16 = (f16acc_t)0.0f;
    const char* Kbase = (const char*)&Kl[buf][0];
    __builtin_amdgcn_s_setprio(1);
    #pragma unroll
    for (int kt = 0; kt < 16; ++kt) {
      bfrag_t kf = *reinterpret_cast<const bfrag_t*>(
          Kbase + l31 * 512 + ((kt * 32 + hi * 16) ^ ksw));
      s16 = mfma32(kf, qf[kt], s16);
    }
    __builtin_amdgcn_s_setprio(0);
    // ---- softmax (base-2): lane owns q = q0+l31; 16 kv in regs; one shfl ---
    // max via v_max3 triples (depth 3)
    float a0 = fmaxf(fmaxf(s16[0], s16[1]), s16[2]);
    float a1 = fmaxf(fmaxf(s16[3], s16[4]), s16[5]);
    float a2 = fmaxf(fmaxf(s16[6], s16[7]), s16[8]);
    float a3 = fmaxf(fmaxf(s16[9], s16[10]), s16[11]);
    float a4 = fmaxf(fmaxf(s16[12], s16[13]), s16[14]);
    float b0 = fmaxf(fmaxf(a0, a1), a2);
    float b1 = fmaxf(fmaxf(a3, a4), s16[15]);
    float mx = fmaxf(b0, b1);
    mx = fmaxf(mx, __shfl_xor(mx, 32));
    if (mx > mrow + 11.0f) {                // defer-max rescale (2^11 headroom)
      float sf = fexp2(mrow - mx);
      mrow = mx;
      lsum *= sf;
      #pragma unroll
      for (int nt = 0; nt < 8; ++nt) o32[nt] *= sf;
    }
    float pe[16];
    float ls = 0.0f;
    #pragma unroll
    for (int i = 0; i < 16; ++i) {
      pe[i] = fexp2(s16[i] - mrow);
      ls += pe[i];
    }
    lsum += ls;
    // ---- P -> bf16 B-frags (register-order; cvt_pk pairs) ----
    i4_t w0, w1;
    w0.x = cvtpk(pe[0], pe[1]);  w0.y = cvtpk(pe[2], pe[3]);
    w0.z = cvtpk(pe[4], pe[5]);  w0.w = cvtpk(pe[6], pe[7]);
    w1.x = cvtpk(pe[8], pe[9]);  w1.y = cvtpk(pe[10], pe[11]);
    w1.z = cvtpk(pe[12], pe[13]); w1.w = cvtpk(pe[14], pe[15]);
    bfrag_t pb0 = __builtin_bit_cast(bfrag_t, w0);
    bfrag_t pb1 = __builtin_bit_cast(bfrag_t, w1);
    // ---- O^T += V^T P^T : 8 d-blocks x 2 ----
    const char* Vbase = (const char*)&Vl[buf][0];
    __builtin_amdgcn_s_setprio(1);
    #pragma unroll
    for (int nt = 0; nt < 8; ++nt) {
      const char* vb = Vbase + (nt * 32 + l31) * 64;
      bfrag_t v0 = *reinterpret_cast<const bfrag_t*>(vb + ((hi * 16) ^ vsw));
      o32[nt] = mfma32(v0, pb0, o32[nt]);
      bfrag_t v1 = *reinterpret_cast<const bfrag_t*>(vb + ((32 + hi * 16) ^ vsw));
      o32[nt] = mfma32(v1, pb1, o32[nt]);
    }
    __builtin_amdgcn_s_setprio(0);
    asm volatile("s_waitcnt vmcnt(0)" ::: "memory");
    __syncthreads();
    buf ^= 1;
  }

  // ---- epilogue ----
  lsum += __shfl_xor(lsum, 32);
  float* Pd = (SPLIT == 1 || part == 0)
                  ? P0 : PX + (size_t)(part - 1) * ((size_t)B_ * S_ * D_);
  float* Og = Pd + ((size_t)b * S_ + q0 + l31) * D_;
  if constexpr (SPLIT == 1) {
    float inv = 1.0f / lsum;
    #pragma unroll
    for (int nt = 0; nt < 8; ++nt)
      #pragma unroll
      for (int gg = 0; gg < 4; ++gg) {
        float4 o;
        o.x = o32[nt][gg * 4 + 0] * inv; o.y = o32[nt][gg * 4 + 1] * inv;
        o.z = o32[nt][gg * 4 + 2] * inv; o.w = o32[nt][gg * 4 + 3] * inv;
        *reinterpret_cast<float4*>(Og + nt * 32 + hi * 4 + gg * 8) = o;
      }
  } else {
    #pragma unroll
    for (int nt = 0; nt < 8; ++nt)
      #pragma unroll
      for (int gg = 0; gg < 4; ++gg) {
        float4 o;
        o.x = o32[nt][gg * 4 + 0]; o.y = o32[nt][gg * 4 + 1];
        o.z = o32[nt][gg * 4 + 2]; o.w = o32[nt][gg * 4 + 3];
        *reinterpret_cast<float4*>(Og + nt * 32 + hi * 4 + gg * 8) = o;
      }
    if (lane < 32) {
      float2 ml; ml.x = mrow; ml.y = lsum;  // base-2 domain
      ML[part * (B_ * S_) + b * S_ + q0 + l31] = ml;
    }
  }
}

// ---- combine SPLIT kv-part partials (base-2 weights) -----------------------
template<int SPLIT>
__global__ __launch_bounds__(256) void combineN(
    const float* __restrict__ PX, const float2* __restrict__ ML,
    float* __restrict__ Out) {
  const int r = blockIdx.x * 4 + (threadIdx.x >> 6);
  const int d4 = (threadIdx.x & 63) * 4;
  float2 ml[SPLIT];
  #pragma unroll
  for (int p = 0; p < SPLIT; ++p) ml[p] = ML[p * (B_ * S_) + r];
  float m = ml[0].x;
  #pragma unroll
  for (int p = 1; p < SPLIT; ++p) m = fmaxf(m, ml[p].x);
  float w[SPLIT];
  float denom = 0.0f;
  #pragma unroll
  for (int p = 0; p < SPLIT; ++p) {
    w[p] = fexp2(ml[p].x - m);
    denom += ml[p].y * w[p];
  }
  float inv = 1.0f / denom;
  size_t idx = (size_t)r * D_ + d4;
  float4 x = *reinterpret_cast<float4*>(Out + idx);
  float4 acc;
  acc.x = x.x * w[0]; acc.y = x.y * w[0]; acc.z = x.z * w[0]; acc.w = x.w * w[0];
  #pragma unroll
  for (int p = 1; p < SPLIT; ++p) {
    float4 y = *reinterpret_cast<const float4*>(
        PX + (size_t)(p - 1) * ((size_t)B_ * S_ * D_) + idx);
    acc.x += y.x * w[p]; acc.y += y.y * w[p];
    acc.z += y.z * w[p]; acc.w += y.w * w[p];
  }
  acc.x *= inv; acc.y *= inv; acc.z *= inv; acc.w *= inv;
  *reinterpret_cast<float4*>(Out + idx) = acc;
}

extern "C" void kernel_launch(void* const* d_in, const int* in_sizes, int n_in,
                              void* d_out, int out_size, void* d_ws, size_t ws_size,
                              hipStream_t stream) {
  const float* X  = (const float*)d_in[0];
  const float* Wq = (const float*)d_in[1];
  const float* Wk = (const float*)d_in[2];
  const float* Wv = (const float*)d_in[3];
  float* out = (float*)d_out;

  char* ws = (char*)d_ws;
  short* Qb = (short*)(ws);                       // 8 MB
  short* Kb = (short*)(ws + 8388608);             // 8 MB
  short* VT = (short*)(ws + 16777216);            // 8 MB (V^T, slot-permuted)
  short* WT = (short*)(ws + 25165824);            // 384 KB
  float2* ML = (float2*)(ws + 25690112);          // 512 KB (m,l per part)
  float* PX  = (float*)(ws + 26214400);           // up to 3 x 16 MB partials
  const size_t NP = (size_t)B_ * S_ * D_ * 4;
  const size_t need4 = 26214400 + 3 * NP;
  const size_t need2 = 26214400 + 1 * NP;

  wt_kernel<<<12, 256, 0, stream>>>(Wq, Wk, Wv, WT);
  proj_kernel<<<768, 256, 0, stream>>>(X, WT, Qb, Kb, VT);
  if (ws_size >= need4) {
    attn32<4><<<512, 256, 0, stream>>>(Qb, Kb, VT, out, PX, ML);
    combineN<4><<<(B_ * S_) / 4, 256, 0, stream>>>(PX, ML, out);
  } else if (ws_size >= need2) {
    attn32<2><<<256, 256, 0, stream>>>(Qb, Kb, VT, out, PX, ML);
    combineN<2><<<(B_ * S_) / 4, 256, 0, stream>>>(PX, ML, out);
  } else {
    attn32<1><<<128, 256, 0, stream>>>(Qb, Kb, VT, out, PX, (float2*)out);
  }
}